// Round 1
// baseline (253.912 us; speedup 1.0000x reference)
//
#include <hip/hip_runtime.h>

// Problem constants (from reference setup_inputs):
//   kernel:  (N=8, K2=25, H=128, W=128) fp32
//   low_fea: (N=8, C=256, H=128, W=128) fp32
//   out[n,c,y,x] = low_fea[n,c,y,x] * S[n,y,x]
//   S[n,y,x]  = sum_{a,b in [0,5)} kernel[n, a*5+b, y+2-a, x+2-b]  (0 outside bounds)
#define NN 8
#define CC 256
#define HH 128
#define WW 128
#define KK 5
#define PAD 2

// One block per (n, y): stage S[x] for the row in LDS, then stream all 256
// channels of that row with float4 loads/stores.
__global__ __launch_bounds__(256) void fused_scale_kernel(
    const float* __restrict__ kern,
    const float* __restrict__ low,
    float* __restrict__ out)
{
    __shared__ __align__(16) float S[WW];

    const int blk = blockIdx.x;        // 0 .. N*H-1
    const int n   = blk >> 7;          // / HH
    const int y   = blk & (HH - 1);
    const int tid = threadIdx.x;

    // --- Stage 1: S[x] for this (n, y) row -------------------------------
    if (tid < WW) {
        const int x = tid;
        float s = 0.0f;
        const float* kb = kern + (size_t)n * (KK * KK) * HH * WW;
#pragma unroll
        for (int a = 0; a < KK; ++a) {
            const int yy = y + PAD - a;
            if (yy >= 0 && yy < HH) {
#pragma unroll
                for (int b = 0; b < KK; ++b) {
                    const int xx = x + PAD - b;
                    if (xx >= 0 && xx < WW) {
                        s += kb[((size_t)(a * KK + b) * HH + yy) * WW + xx];
                    }
                }
            }
        }
        S[x] = s;
    }
    __syncthreads();

    // --- Stage 2: out[n,c,y,:] = low[n,c,y,:] * S[:] for all c ------------
    // Row-set has CC*WW = 32768 floats = 8192 float4; 256 threads -> 32 iters.
    // j = it*256 + tid  ->  xq = tid & 31 (loop-invariant), c = it*8 + tid>>5.
    const float4* lf4  = (const float4*)low;
    float4*       out4 = (float4*)out;
    const size_t base4 = (((size_t)n * CC * HH + (size_t)y) * WW) >> 2; // [n][0][y][0] in float4
    const int    xq    = tid & 31;                 // float4 index within row
    const float4 s4    = *(const float4*)&S[xq * 4];

#pragma unroll 8
    for (int it = 0; it < 32; ++it) {
        const int    c   = it * 8 + (tid >> 5);
        const size_t idx = base4 + (size_t)c * (HH * WW / 4) + (size_t)xq;
        float4 v = lf4[idx];
        float4 r;
        r.x = v.x * s4.x;
        r.y = v.y * s4.y;
        r.z = v.z * s4.z;
        r.w = v.w * s4.w;
        out4[idx] = r;
    }
}

extern "C" void kernel_launch(void* const* d_in, const int* in_sizes, int n_in,
                              void* d_out, int out_size, void* d_ws, size_t ws_size,
                              hipStream_t stream) {
    const float* kern = (const float*)d_in[0];  // (8, 25, 128, 128)
    const float* low  = (const float*)d_in[1];  // (8, 256, 128, 128)
    float* out = (float*)d_out;                 // (8, 256, 128, 128)

    dim3 grid(NN * HH);   // 1024 blocks
    dim3 block(256);
    fused_scale_kernel<<<grid, block, 0, stream>>>(kern, low, out);
}

// Round 2
// 251.196 us; speedup vs baseline: 1.0108x; 1.0108x over previous
//
#include <hip/hip_runtime.h>

// kernel:  (N=8, K2=25, H=128, W=128) fp32
// low_fea: (N=8, C=256, H=128, W=128) fp32
// out[n,c,y,x] = low_fea[n,c,y,x] * S[n,y,x]
// S[n,y,x]  = sum_{a,b in [0,5)} kernel[n, a*5+b, y+2-a, x+2-b]  (0 outside bounds)
#define NN 8
#define CC 256
#define HH 128
#define WW 128
#define KK 5
#define PAD 2

// ---------- Kernel A: S[n,y,x] -> d_ws (8*128*128 floats = 512 KB) ----------
// One block (128 threads) per (n,y) row; lane = x. Reads kernel tensor once.
__global__ __launch_bounds__(128) void s_compute_kernel(
    const float* __restrict__ kern, float* __restrict__ S)
{
    const int blk = blockIdx.x;        // 0 .. N*H-1
    const int n   = blk >> 7;
    const int y   = blk & (HH - 1);
    const int x   = threadIdx.x;

    float s = 0.0f;
    const float* kb = kern + (size_t)n * (KK * KK) * HH * WW;
#pragma unroll
    for (int a = 0; a < KK; ++a) {
        const int yy = y + PAD - a;
        if (yy >= 0 && yy < HH) {
#pragma unroll
            for (int b = 0; b < KK; ++b) {
                const int xx = x + PAD - b;
                if (xx >= 0 && xx < WW) {
                    s += kb[((size_t)(a * KK + b) * HH + yy) * WW + xx];
                }
            }
        }
    }
    S[(size_t)blk * WW + x] = s;
}

// ---------- Kernel B: out = low * S[broadcast], pure streaming ----------
// 8192 blocks x 256 threads. Block handles (n, y, 32-channel chunk):
// 4 independent float4 load/store pairs per thread. S read: one float4, L2-hit.
__global__ __launch_bounds__(256) void scale_kernel(
    const float* __restrict__ low,
    const float* __restrict__ S,
    float* __restrict__ out)
{
    const int blk   = blockIdx.x;          // ((n*128 + y)*8 + chunk)
    const int chunk = blk & 7;
    const int row   = blk >> 3;            // n*128 + y
    const int n     = row >> 7;
    const int y     = row & (HH - 1);
    const int tid   = threadIdx.x;
    const int xq    = tid & 31;            // float4 index within row (W/4 = 32)

    const float4 s4 = ((const float4*)(S + (size_t)row * WW))[xq];

    const float4* lf4  = (const float4*)low;
    float4*       out4 = (float4*)out;
    const size_t base4 = ((size_t)n * CC * HH + (size_t)y) * (WW / 4); // (n,0,y,0)
    const int    c0    = chunk * 32 + (tid >> 5);

#pragma unroll
    for (int it = 0; it < 4; ++it) {
        const int    c   = c0 + it * 8;
        const size_t idx = base4 + (size_t)c * (HH * WW / 4) + (size_t)xq;
        float4 v = lf4[idx];
        float4 r;
        r.x = v.x * s4.x;
        r.y = v.y * s4.y;
        r.z = v.z * s4.z;
        r.w = v.w * s4.w;
        out4[idx] = r;
    }
}

// ---------- Fallback (round-1 fused kernel) if ws too small ----------
__global__ __launch_bounds__(256) void fused_scale_kernel(
    const float* __restrict__ kern,
    const float* __restrict__ low,
    float* __restrict__ out)
{
    __shared__ __align__(16) float S[WW];
    const int blk = blockIdx.x;
    const int n   = blk >> 7;
    const int y   = blk & (HH - 1);
    const int tid = threadIdx.x;

    if (tid < WW) {
        const int x = tid;
        float s = 0.0f;
        const float* kb = kern + (size_t)n * (KK * KK) * HH * WW;
#pragma unroll
        for (int a = 0; a < KK; ++a) {
            const int yy = y + PAD - a;
            if (yy >= 0 && yy < HH) {
#pragma unroll
                for (int b = 0; b < KK; ++b) {
                    const int xx = x + PAD - b;
                    if (xx >= 0 && xx < WW) {
                        s += kb[((size_t)(a * KK + b) * HH + yy) * WW + xx];
                    }
                }
            }
        }
        S[x] = s;
    }
    __syncthreads();

    const float4* lf4  = (const float4*)low;
    float4*       out4 = (float4*)out;
    const size_t base4 = (((size_t)n * CC * HH + (size_t)y) * WW) >> 2;
    const int    xq    = tid & 31;
    const float4 s4    = *(const float4*)&S[xq * 4];

#pragma unroll 8
    for (int it = 0; it < 32; ++it) {
        const int    c   = it * 8 + (tid >> 5);
        const size_t idx = base4 + (size_t)c * (HH * WW / 4) + (size_t)xq;
        float4 v = lf4[idx];
        float4 r;
        r.x = v.x * s4.x;
        r.y = v.y * s4.y;
        r.z = v.z * s4.z;
        r.w = v.w * s4.w;
        out4[idx] = r;
    }
}

extern "C" void kernel_launch(void* const* d_in, const int* in_sizes, int n_in,
                              void* d_out, int out_size, void* d_ws, size_t ws_size,
                              hipStream_t stream) {
    const float* kern = (const float*)d_in[0];  // (8, 25, 128, 128)
    const float* low  = (const float*)d_in[1];  // (8, 256, 128, 128)
    float* out = (float*)d_out;                 // (8, 256, 128, 128)

    const size_t s_bytes = (size_t)NN * HH * WW * sizeof(float);  // 512 KB

    if (ws_size >= s_bytes) {
        float* S = (float*)d_ws;
        s_compute_kernel<<<dim3(NN * HH), dim3(128), 0, stream>>>(kern, S);
        scale_kernel<<<dim3(NN * HH * 8), dim3(256), 0, stream>>>(low, S, out);
    } else {
        fused_scale_kernel<<<dim3(NN * HH), dim3(256), 0, stream>>>(kern, low, out);
    }
}